// Round 2
// baseline (1066.954 us; speedup 1.0000x reference)
//
#include <hip/hip_runtime.h>
#include <stdint.h>
#include <math.h>

#define NB 16
#define NS 512
#define NH 12
#define ND 64
#define NE 768   // d_model
#define NF 768   // inner = NH*ND

// ---------------- K0: probe attention_mask storage dtype ----------------
// bool may be pushed as 1-byte (np.bool_) or 4-byte (int32). For byte storage
// of an (almost-)all-true mask, bytes at offsets %4!=0 are nonzero; for int32
// storage of 0/1 values those bytes are always zero.
__global__ __launch_bounds__(256) void mask_probe_kernel(const unsigned char* __restrict__ m,
                                                         int* __restrict__ flag) {
    __shared__ int any;
    if (threadIdx.x == 0) any = 0;
    __syncthreads();
    int acc = 0;
    for (int i = threadIdx.x; i < NB * NS; i += 256) {
        if ((i & 3) && m[i]) acc = 1;
    }
    if (acc) atomicOr(&any, 1);
    __syncthreads();
    if (threadIdx.x == 0) *flag = any;   // 1 = byte storage, 0 = int32 storage
}

// ---------------- K1: rope tables ----------------
__global__ __launch_bounds__(256) void rope_table_kernel(float* __restrict__ cos_t,
                                                         float* __restrict__ sin_t) {
    int i = blockIdx.x * 256 + threadIdx.x;
    if (i >= NS * 32) return;
    int p = i >> 5;
    int j = i & 31;
    float inv_freq = powf(10000.0f, -(float)j / 32.0f);
    float ang = (float)p * inv_freq;
    cos_t[i] = cosf(ang);
    sin_t[i] = sinf(ang);
}

// ---------------- K2: QKV projection ----------------
// X (8192 x 768) @ W (768 x 768) -> out in (b,h,s,d) layout
__global__ __launch_bounds__(256) void proj_kernel(const float* __restrict__ X,
    const float* __restrict__ Wq, const float* __restrict__ Wk, const float* __restrict__ Wv,
    float* __restrict__ qo, float* __restrict__ ko, float* __restrict__ vo)
{
    const float* W = (blockIdx.z == 0) ? Wq : (blockIdx.z == 1) ? Wk : Wv;
    float*       O = (blockIdx.z == 0) ? qo : (blockIdx.z == 1) ? ko : vo;
    __shared__ float As[8][132];
    __shared__ float Bs[8][132];
    const int tid = threadIdx.x;
    const int m0 = blockIdx.y * 128;
    const int n0 = blockIdx.x * 128;
    const int ty = tid >> 4, tx = tid & 15;
    const int arow = tid >> 1, acol = (tid & 1) * 4;
    const int brow = tid >> 5, bcol = (tid & 31) * 4;
    float acc[8][8];
    #pragma unroll
    for (int i = 0; i < 8; ++i)
        #pragma unroll
        for (int j = 0; j < 8; ++j) acc[i][j] = 0.f;

    for (int k0 = 0; k0 < NE; k0 += 8) {
        float4 av = *(const float4*)&X[(m0 + arow) * NE + k0 + acol];
        float4 bv = *(const float4*)&W[(k0 + brow) * NF + n0 + bcol];
        __syncthreads();
        As[acol + 0][arow] = av.x;
        As[acol + 1][arow] = av.y;
        As[acol + 2][arow] = av.z;
        As[acol + 3][arow] = av.w;
        *(float4*)&Bs[brow][bcol] = bv;
        __syncthreads();
        #pragma unroll
        for (int kk = 0; kk < 8; ++kk) {
            float a[8], b[8];
            *(float4*)&a[0] = *(const float4*)&As[kk][ty * 8];
            *(float4*)&a[4] = *(const float4*)&As[kk][ty * 8 + 4];
            *(float4*)&b[0] = *(const float4*)&Bs[kk][tx * 8];
            *(float4*)&b[4] = *(const float4*)&Bs[kk][tx * 8 + 4];
            #pragma unroll
            for (int i = 0; i < 8; ++i)
                #pragma unroll
                for (int j = 0; j < 8; ++j)
                    acc[i][j] = fmaf(a[i], b[j], acc[i][j]);
        }
    }
    #pragma unroll
    for (int i = 0; i < 8; ++i) {
        int r = m0 + ty * 8 + i;
        int bb = r >> 9, ss = r & 511;
        #pragma unroll
        for (int j = 0; j < 8; j += 4) {
            int c = n0 + tx * 8 + j;
            int hh = c >> 6, dd = c & 63;
            float4 val = make_float4(acc[i][j], acc[i][j+1], acc[i][j+2], acc[i][j+3]);
            *(float4*)&O[(((size_t)bb * NH + hh) * NS + ss) * ND + dd] = val;
        }
    }
}

// ---------------- K4: output projection ----------------
// A (8192 x 768) @ Wo (768 x 768) -> out (8192 x 768) row-major
__global__ __launch_bounds__(256) void outproj_kernel(const float* __restrict__ A,
    const float* __restrict__ Wo, float* __restrict__ out)
{
    __shared__ float As[8][132];
    __shared__ float Bs[8][132];
    const int tid = threadIdx.x;
    const int m0 = blockIdx.y * 128;
    const int n0 = blockIdx.x * 128;
    const int ty = tid >> 4, tx = tid & 15;
    const int arow = tid >> 1, acol = (tid & 1) * 4;
    const int brow = tid >> 5, bcol = (tid & 31) * 4;
    float acc[8][8];
    #pragma unroll
    for (int i = 0; i < 8; ++i)
        #pragma unroll
        for (int j = 0; j < 8; ++j) acc[i][j] = 0.f;

    for (int k0 = 0; k0 < NF; k0 += 8) {
        float4 av = *(const float4*)&A[(m0 + arow) * NF + k0 + acol];
        float4 bv = *(const float4*)&Wo[(k0 + brow) * NE + n0 + bcol];
        __syncthreads();
        As[acol + 0][arow] = av.x;
        As[acol + 1][arow] = av.y;
        As[acol + 2][arow] = av.z;
        As[acol + 3][arow] = av.w;
        *(float4*)&Bs[brow][bcol] = bv;
        __syncthreads();
        #pragma unroll
        for (int kk = 0; kk < 8; ++kk) {
            float a[8], b[8];
            *(float4*)&a[0] = *(const float4*)&As[kk][ty * 8];
            *(float4*)&a[4] = *(const float4*)&As[kk][ty * 8 + 4];
            *(float4*)&b[0] = *(const float4*)&Bs[kk][tx * 8];
            *(float4*)&b[4] = *(const float4*)&Bs[kk][tx * 8 + 4];
            #pragma unroll
            for (int i = 0; i < 8; ++i)
                #pragma unroll
                for (int j = 0; j < 8; ++j)
                    acc[i][j] = fmaf(a[i], b[j], acc[i][j]);
        }
    }
    #pragma unroll
    for (int i = 0; i < 8; ++i) {
        int r = m0 + ty * 8 + i;
        #pragma unroll
        for (int j = 0; j < 8; j += 4) {
            int c = n0 + tx * 8 + j;
            float4 val = make_float4(acc[i][j], acc[i][j+1], acc[i][j+2], acc[i][j+3]);
            *(float4*)&out[(size_t)r * NE + c] = val;
        }
    }
}

// ---------------- K3: chain-aware flash attention ----------------
// grid: (8 q-tiles, 12 heads, 16 batch), 256 threads
// q,k,v in (b,h,s,d); out aout in (b,s,h*d)
__global__ __launch_bounds__(256) void attn_kernel(
    const float* __restrict__ q, const float* __restrict__ k, const float* __restrict__ v,
    const float* __restrict__ cos_t, const float* __restrict__ sin_t,
    const int* __restrict__ chain, const void* __restrict__ amask,
    const int* __restrict__ mask_is_u8, float* __restrict__ aout)
{
    const int b = blockIdx.z, h = blockIdx.y, q0 = blockIdx.x * 64;
    __shared__ float Qr[64][68];   // [d][qrow] raw
    __shared__ float Qp[64][68];   // [d][qrow] roped
    __shared__ float Kr[64][36];   // [d][key] raw
    __shared__ float Kp[64][36];   // [d][key] roped; V[32][68] reuses this after scores
    __shared__ float Sm[64][36];   // [qrow][key] merged scores -> P
    __shared__ float mrow[64], lrow[64], frow[64];
    __shared__ int   cq[64], ck[32];
    __shared__ float kbias[32];

    const int tid = threadIdx.x;
    const int ty = tid >> 4, tx = tid & 15;
    const int m_u8 = *mask_is_u8;
    const float* qb = q + (((size_t)b * NH + h) * NS + q0) * ND;

    // load Q tile (coalesced), transpose into LDS
    for (int i = tid; i < 64 * 64; i += 256) {
        int row = i >> 6, d = i & 63;
        Qr[d][row] = qb[row * ND + d];
    }
    if (tid < 64) {
        cq[tid] = chain[b * NS + q0 + tid];
        mrow[tid] = -INFINITY;
        lrow[tid] = 0.f;
    }
    __syncthreads();
    // rope Q
    for (int i = tid; i < 64 * 32; i += 256) {
        int row = i >> 5, j = i & 31;
        float c = cos_t[(q0 + row) * 32 + j];
        float s = sin_t[(q0 + row) * 32 + j];
        float t1 = Qr[j][row], t2 = Qr[j + 32][row];
        Qp[j][row]      = t1 * c - t2 * s;
        Qp[j + 32][row] = t1 * s + t2 * c;
    }

    float accO[4][4];
    #pragma unroll
    for (int i = 0; i < 4; ++i)
        #pragma unroll
        for (int j = 0; j < 4; ++j) accO[i][j] = 0.f;

    float* Vs = &Kp[0][0];   // V[key][dv] with stride 68, 32*68 <= 64*36

    for (int kt = 0; kt < NS / 32; ++kt) {
        const int kbase = kt * 32;
        const float* kb = k + (((size_t)b * NH + h) * NS + kbase) * ND;
        const float* vb = v + (((size_t)b * NH + h) * NS + kbase) * ND;
        __syncthreads();   // previous iteration done with Kr/Kp/Vs/Sm
        for (int i = tid; i < 32 * 64; i += 256) {
            int key = i >> 6, d = i & 63;
            Kr[d][key] = kb[key * ND + d];
        }
        if (tid < 32) {
            ck[tid] = chain[b * NS + kbase + tid];
            int idx = b * NS + kbase + tid;
            int ok = m_u8 ? (int)((const unsigned char*)amask)[idx]
                          : ((const int*)amask)[idx];
            kbias[tid] = ok ? 0.f : -INFINITY;
        }
        __syncthreads();
        // rope K
        for (int i = tid; i < 32 * 32; i += 256) {
            int key = i >> 5, j = i & 31;
            float c = cos_t[(kbase + key) * 32 + j];
            float s = sin_t[(kbase + key) * 32 + j];
            float t1 = Kr[j][key], t2 = Kr[j + 32][key];
            Kp[j][key]      = t1 * c - t2 * s;
            Kp[j + 32][key] = t1 * s + t2 * c;
        }
        __syncthreads();
        // scores: each thread 4 q-rows (ty) x 2 keys (tx), both variants
        float s_raw[4][2], s_rop[4][2];
        #pragma unroll
        for (int i = 0; i < 4; ++i)
            #pragma unroll
            for (int j = 0; j < 2; ++j) { s_raw[i][j] = 0.f; s_rop[i][j] = 0.f; }
        #pragma unroll 4
        for (int kk = 0; kk < 64; ++kk) {
            float a_r[4], a_p[4], b_r[2], b_p[2];
            *(float4*)a_r = *(const float4*)&Qr[kk][ty * 4];
            *(float4*)a_p = *(const float4*)&Qp[kk][ty * 4];
            b_r[0] = Kr[kk][tx * 2]; b_r[1] = Kr[kk][tx * 2 + 1];
            b_p[0] = Kp[kk][tx * 2]; b_p[1] = Kp[kk][tx * 2 + 1];
            #pragma unroll
            for (int i = 0; i < 4; ++i)
                #pragma unroll
                for (int j = 0; j < 2; ++j) {
                    s_raw[i][j] = fmaf(a_r[i], b_r[j], s_raw[i][j]);
                    s_rop[i][j] = fmaf(a_p[i], b_p[j], s_rop[i][j]);
                }
        }
        #pragma unroll
        for (int i = 0; i < 4; ++i)
            #pragma unroll
            for (int j = 0; j < 2; ++j) {
                int qrow = ty * 4 + i, key = tx * 2 + j;
                bool intra = (cq[qrow] == ck[key]);
                Sm[qrow][key] = (intra ? s_rop[i][j] : s_raw[i][j]) * 0.125f + kbias[key];
            }
        __syncthreads();
        // wave 0: online softmax update; waves 1-3: load V (overwrites Kp region)
        if (tid < 64) {
            int row = tid;
            float m_old = mrow[row];
            float tmax = -INFINITY;
            #pragma unroll 8
            for (int t = 0; t < 32; ++t) tmax = fmaxf(tmax, Sm[row][t]);
            float mnew = fmaxf(m_old, tmax);
            float fac, psum = 0.f;
            if (mnew == -INFINITY) {
                fac = 1.f;
                for (int t = 0; t < 32; ++t) Sm[row][t] = 0.f;
            } else {
                fac = expf(m_old - mnew);
                #pragma unroll 8
                for (int t = 0; t < 32; ++t) {
                    float p = expf(Sm[row][t] - mnew);
                    Sm[row][t] = p;
                    psum += p;
                }
            }
            mrow[row] = mnew;
            lrow[row] = lrow[row] * fac + psum;
            frow[row] = fac;
        } else {
            for (int i = tid - 64; i < 32 * 64; i += 192) {
                int key = i >> 6, d = i & 63;
                Vs[key * 68 + d] = vb[key * ND + d];
            }
        }
        __syncthreads();
        // PV: each thread 4 q-rows (ty) x 4 dv (tx)
        float f[4];
        #pragma unroll
        for (int i = 0; i < 4; ++i) f[i] = frow[ty * 4 + i];
        #pragma unroll
        for (int i = 0; i < 4; ++i)
            #pragma unroll
            for (int j = 0; j < 4; ++j) accO[i][j] *= f[i];
        #pragma unroll 4
        for (int kk = 0; kk < 32; ++kk) {
            float a[4], bv4[4];
            a[0] = Sm[ty * 4 + 0][kk];
            a[1] = Sm[ty * 4 + 1][kk];
            a[2] = Sm[ty * 4 + 2][kk];
            a[3] = Sm[ty * 4 + 3][kk];
            *(float4*)bv4 = *(const float4*)&Vs[kk * 68 + tx * 4];
            #pragma unroll
            for (int i = 0; i < 4; ++i)
                #pragma unroll
                for (int j = 0; j < 4; ++j)
                    accO[i][j] = fmaf(a[i], bv4[j], accO[i][j]);
        }
    }
    __syncthreads();
    #pragma unroll
    for (int i = 0; i < 4; ++i) {
        int row = ty * 4 + i;
        float l = lrow[row];
        float inv = (l > 0.f) ? 1.f / l : 0.f;   // nan_to_num for fully-masked rows
        float4 val = make_float4(accO[i][0] * inv, accO[i][1] * inv,
                                 accO[i][2] * inv, accO[i][3] * inv);
        *(float4*)&aout[((size_t)(b * NS + q0 + row)) * NF + h * ND + tx * 4] = val;
    }
}

extern "C" void kernel_launch(void* const* d_in, const int* in_sizes, int n_in,
                              void* d_out, int out_size, void* d_ws, size_t ws_size,
                              hipStream_t stream) {
    const float* x     = (const float*)d_in[0];
    const int*   chain = (const int*)d_in[1];
    const void*  amask = d_in[2];
    const float* Wq = (const float*)d_in[3];
    const float* Wk = (const float*)d_in[4];
    const float* Wv = (const float*)d_in[5];
    const float* Wo = (const float*)d_in[6];
    float* out = (float*)d_out;

    float* wsf   = (float*)d_ws;
    float* cos_t = wsf;                   // 512*32
    float* sin_t = cos_t + NS * 32;       // 512*32
    float* qb    = sin_t + NS * 32;       // 16*12*512*64
    const size_t QSZ = (size_t)NB * NH * NS * ND;
    float* kb    = qb + QSZ;
    float* vb    = kb + QSZ;
    float* aout  = vb + QSZ;              // 16*512*768
    int*   mflag = (int*)(aout + (size_t)NB * NS * NF);

    mask_probe_kernel<<<dim3(1), dim3(256), 0, stream>>>((const unsigned char*)amask, mflag);
    rope_table_kernel<<<dim3(64), dim3(256), 0, stream>>>(cos_t, sin_t);
    proj_kernel<<<dim3(6, 64, 3), dim3(256), 0, stream>>>(x, Wq, Wk, Wv, qb, kb, vb);
    attn_kernel<<<dim3(8, 12, 16), dim3(256), 0, stream>>>(qb, kb, vb, cos_t, sin_t,
                                                           chain, amask, mflag, aout);
    outproj_kernel<<<dim3(6, 64, 1), dim3(256), 0, stream>>>(aout, Wo, out);
}

// Round 3
// 180.297 us; speedup vs baseline: 5.9178x; 5.9178x over previous
//
#include <hip/hip_runtime.h>
#include <stdint.h>
#include <math.h>

#define NB 16
#define NS 512
#define NH 12
#define ND 64
#define NE 768
#define NF 768

typedef __attribute__((ext_vector_type(4))) float  f32x4;
typedef __attribute__((ext_vector_type(8))) short  bf16x8;
typedef __attribute__((ext_vector_type(4))) short  bf16x4;

__device__ __forceinline__ short f2bf(float f) {
    unsigned u = __builtin_bit_cast(unsigned, f);
    u += 0x7FFFu + ((u >> 16) & 1u);
    return (short)(u >> 16);
}
__device__ __forceinline__ float bf2f(short s) {
    unsigned u = ((unsigned)(unsigned short)s) << 16;
    return __builtin_bit_cast(float, u);
}

#define MFMA16(a, b, c) __builtin_amdgcn_mfma_f32_16x16x32_bf16((a), (b), (c), 0, 0, 0)

// swizzled LDS tile access: tiles are [rows][64] bf16 (128 B rows), byte ^= ((row&7)<<4)
__device__ __forceinline__ bf16x8 lds_rd8(const short* base, int row, int cb) {
    return *(const bf16x8*)((const char*)base + (((row) * 128 + (cb)) ^ (((row) & 7) << 4)));
}

// ---------------- K0: probe attention_mask storage dtype ----------------
__global__ __launch_bounds__(256) void mask_probe_kernel(const unsigned char* __restrict__ m,
                                                         int* __restrict__ flag) {
    __shared__ int any;
    if (threadIdx.x == 0) any = 0;
    __syncthreads();
    int acc = 0;
    for (int i = threadIdx.x; i < NB * NS; i += 256) {
        if ((i & 3) && m[i]) acc = 1;
    }
    if (acc) atomicOr(&any, 1);
    __syncthreads();
    if (threadIdx.x == 0) *flag = any;   // 1 = byte storage, 0 = int32 storage
}

// ---------------- K1: rope tables (fp32) ----------------
__global__ __launch_bounds__(256) void rope_table_kernel(float* __restrict__ cos_t,
                                                         float* __restrict__ sin_t) {
    int i = blockIdx.x * 256 + threadIdx.x;
    if (i >= NS * 32) return;
    int p = i >> 5;
    int j = i & 31;
    float inv_freq = powf(10000.0f, -(float)j / 32.0f);
    float ang = (float)p * inv_freq;
    cos_t[i] = cosf(ang);
    sin_t[i] = sinf(ang);
}

// ---------------- K2: convert x fp32 -> bf16 ----------------
__global__ __launch_bounds__(256) void convert_x_kernel(const float* __restrict__ x,
                                                        short* __restrict__ xb) {
    int i = (blockIdx.x * 256 + threadIdx.x) * 8;
    if (i >= 8192 * 768) return;
    float4 a = *(const float4*)&x[i];
    float4 b = *(const float4*)&x[i + 4];
    bf16x8 r = { f2bf(a.x), f2bf(a.y), f2bf(a.z), f2bf(a.w),
                 f2bf(b.x), f2bf(b.y), f2bf(b.z), f2bf(b.w) };
    *(bf16x8*)&xb[i] = r;
}

// ---------------- K3: transpose + convert weights: W[k][n] fp32 -> Wt[n][k] bf16 ----------------
__global__ __launch_bounds__(256) void convert_wt_kernel(
    const float* __restrict__ Wq, const float* __restrict__ Wk,
    const float* __restrict__ Wv, const float* __restrict__ Wo,
    short* __restrict__ Wqt, short* __restrict__ Wkt,
    short* __restrict__ Wvt, short* __restrict__ Wot) {
    const float* W  = (blockIdx.z == 0) ? Wq  : (blockIdx.z == 1) ? Wk  : (blockIdx.z == 2) ? Wv  : Wo;
    short*       Wt = (blockIdx.z == 0) ? Wqt : (blockIdx.z == 1) ? Wkt : (blockIdx.z == 2) ? Wvt : Wot;
    const int k0 = blockIdx.y * 64, n0 = blockIdx.x * 64;
    __shared__ float t[64][65];
    for (int u = threadIdx.x; u < 4096; u += 256) {
        int r = u >> 6, c = u & 63;
        t[r][c] = W[(size_t)(k0 + r) * 768 + n0 + c];
    }
    __syncthreads();
    for (int u = threadIdx.x; u < 4096; u += 256) {
        int c = u >> 6, r = u & 63;
        Wt[(size_t)(n0 + c) * 768 + k0 + r] = f2bf(t[r][c]);
    }
}

// ---------------- K4: QKV projection GEMM (bf16 MFMA) ----------------
// A = xb [8192][768], Bt = Wt [768 n][768 k]; C -> q/k/v in (b,h,s,d) bf16
__global__ __launch_bounds__(256) void gemm_qkv_kernel(const short* __restrict__ xb,
    const short* __restrict__ Wqt, const short* __restrict__ Wkt, const short* __restrict__ Wvt,
    short* __restrict__ qo, short* __restrict__ ko, short* __restrict__ vo) {
    const int z = blockIdx.z;
    const short* Bt = (z == 0) ? Wqt : (z == 1) ? Wkt : Wvt;
    short*       O  = (z == 0) ? qo  : (z == 1) ? ko  : vo;
    const int n0 = blockIdx.x * 128, m0 = blockIdx.y * 128;
    __shared__ short As[128 * 64], Bs[128 * 64];
    const int tid = threadIdx.x, lane = tid & 63, wave = tid >> 6;
    const int g = lane >> 4, l15 = lane & 15;
    const int wm = wave >> 1, wn = wave & 1;
    f32x4 acc[4][4];
    #pragma unroll
    for (int i = 0; i < 4; ++i)
        #pragma unroll
        for (int j = 0; j < 4; ++j) acc[i][j] = (f32x4){0.f, 0.f, 0.f, 0.f};

    for (int kt = 0; kt < 12; ++kt) {
        __syncthreads();
        const short* Asrc = xb + (size_t)m0 * 768 + kt * 64;
        const short* Bsrc = Bt + (size_t)n0 * 768 + kt * 64;
        #pragma unroll
        for (int p = 0; p < 4; ++p) {
            int u = tid + p * 256;              // 0..1023
            int row = u >> 3, slot = u & 7;
            int off = (row * 128 + slot * 16) ^ ((row & 7) << 4);
            *(bf16x8*)((char*)As + off) = *(const bf16x8*)(Asrc + (size_t)row * 768 + slot * 8);
            *(bf16x8*)((char*)Bs + off) = *(const bf16x8*)(Bsrc + (size_t)row * 768 + slot * 8);
        }
        __syncthreads();
        #pragma unroll
        for (int h2 = 0; h2 < 2; ++h2) {
            bf16x8 af[4], bfr[4];
            const int cb = h2 * 64 + g * 16;
            #pragma unroll
            for (int i = 0; i < 4; ++i) {
                af[i]  = lds_rd8(As, wm * 64 + i * 16 + l15, cb);
                bfr[i] = lds_rd8(Bs, wn * 64 + i * 16 + l15, cb);
            }
            #pragma unroll
            for (int i = 0; i < 4; ++i)
                #pragma unroll
                for (int j = 0; j < 4; ++j)
                    acc[i][j] = MFMA16(af[i], bfr[j], acc[i][j]);
        }
    }
    #pragma unroll
    for (int i = 0; i < 4; ++i)
        #pragma unroll
        for (int r = 0; r < 4; ++r) {
            int m = m0 + wm * 64 + i * 16 + g * 4 + r;
            int bb = m >> 9, ss = m & 511;
            #pragma unroll
            for (int j = 0; j < 4; ++j) {
                int n = n0 + wn * 64 + j * 16 + l15;
                int hh = n >> 6, dd = n & 63;
                O[(((size_t)bb * NH + hh) * NS + ss) * ND + dd] = f2bf(acc[i][j][r]);
            }
        }
}

// ---------------- K5: RoPE(q,k) + transpose(v) ----------------
// reads q_raw,k_raw,v (b,h,s,d bf16); writes q_rope,k_rope (b,h,s,d) and vt (b,h,d,s)
__global__ __launch_bounds__(256) void rope_tr_kernel(
    const short* __restrict__ qr, const short* __restrict__ kr, const short* __restrict__ v,
    const float* __restrict__ cos_t, const float* __restrict__ sin_t,
    short* __restrict__ qp, short* __restrict__ kp, short* __restrict__ vt) {
    const int b = blockIdx.z, h = blockIdx.y, s0 = blockIdx.x * 64;
    const size_t base = (((size_t)b * NH + h) * NS + s0) * ND;
    const int tid = threadIdx.x;
    #pragma unroll
    for (int p = 0; p < 4; ++p) {
        int u = tid + p * 256;                 // 0..1023: tensor u>>9, unit u&511
        int idx = u & 511;
        int s = idx >> 3, jj = (idx & 7) * 4;
        const short* src = (u >> 9) ? kr : qr;
        short*       dst = (u >> 9) ? kp : qp;
        bf16x4 a4 = *(const bf16x4*)(src + base + s * 64 + jj);
        bf16x4 b4 = *(const bf16x4*)(src + base + s * 64 + 32 + jj);
        float4 c4 = *(const float4*)&cos_t[(s0 + s) * 32 + jj];
        float4 s4 = *(const float4*)&sin_t[(s0 + s) * 32 + jj];
        float c[4] = {c4.x, c4.y, c4.z, c4.w};
        float sn[4] = {s4.x, s4.y, s4.z, s4.w};
        bf16x4 o1, o2;
        #pragma unroll
        for (int j = 0; j < 4; ++j) {
            float t1 = bf2f(a4[j]), t2 = bf2f(b4[j]);
            o1[j] = f2bf(t1 * c[j] - t2 * sn[j]);
            o2[j] = f2bf(t1 * sn[j] + t2 * c[j]);
        }
        *(bf16x4*)(dst + base + s * 64 + jj) = o1;
        *(bf16x4*)(dst + base + s * 64 + 32 + jj) = o2;
    }
    // transpose v tile [64 s][64 d] -> vt[d][s]
    __shared__ short tv[64 * 72];
    #pragma unroll
    for (int p = 0; p < 2; ++p) {
        int u = tid + p * 256;
        int s = u >> 3, d8 = (u & 7) * 8;
        bf16x8 vv = *(const bf16x8*)(v + base + s * 64 + d8);
        #pragma unroll
        for (int j = 0; j < 8; ++j) tv[(d8 + j) * 72 + s] = vv[j];
    }
    __syncthreads();
    const size_t vtbase = ((size_t)b * NH + h) * ND * NS + s0;
    #pragma unroll
    for (int p = 0; p < 2; ++p) {
        int u = tid + p * 256;
        int d = u >> 3, s8 = (u & 7) * 8;
        bf16x8 o = *(const bf16x8*)&tv[d * 72 + s8];
        *(bf16x8*)(vt + vtbase + (size_t)d * NS + s8) = o;
    }
}

// ---------------- K6: chain-aware flash attention (bf16 MFMA) ----------------
// grid (8 q-tiles, 12 h, 16 b), 256 thr = 4 waves; each wave owns 16 q-rows.
__global__ __launch_bounds__(256) void attn_mfma_kernel(
    const short* __restrict__ qr, const short* __restrict__ qp,
    const short* __restrict__ kr, const short* __restrict__ kp,
    const short* __restrict__ vt,
    const int* __restrict__ chain, const void* __restrict__ amask,
    const int* __restrict__ mflag, short* __restrict__ aout) {
    const int b = blockIdx.z, h = blockIdx.y, q0 = blockIdx.x * 64;
    __shared__ short Kr_s[64 * 64], Kp_s[64 * 64], Vt_s[64 * 64];
    __shared__ short P_s[4 * 16 * 64];
    __shared__ __align__(16) int   ck_s[64];
    __shared__ __align__(16) float kb_s[64];
    const int tid = threadIdx.x, lane = tid & 63, wave = tid >> 6;
    const int g = lane >> 4, l15 = lane & 15;
    const int m_u8 = *mflag;
    const size_t bh = ((size_t)b * NH + h) * NS;

    // ---- stage Q_raw/Q_rope tiles into Kr_s/Kp_s, grab B-frags ----
    const short* qrs = qr + (bh + q0) * ND;
    const short* qps = qp + (bh + q0) * ND;
    #pragma unroll
    for (int p = 0; p < 2; ++p) {
        int u = tid + p * 256;                  // 0..511 (8 KB tile)
        int off = (u * 16) ^ (((u >> 3) & 7) << 4);
        *(bf16x8*)((char*)Kr_s + off) = *(const bf16x8*)(qrs + u * 8);
        *(bf16x8*)((char*)Kp_s + off) = *(const bf16x8*)(qps + u * 8);
    }
    __syncthreads();
    const int qrow = wave * 16 + l15;
    bf16x8 fqr[2], fqp[2];
    #pragma unroll
    for (int h2 = 0; h2 < 2; ++h2) {
        int cb = h2 * 64 + g * 16;
        fqr[h2] = lds_rd8(Kr_s, qrow, cb);
        fqp[h2] = lds_rd8(Kp_s, qrow, cb);
    }
    const int cqv = chain[b * NS + q0 + qrow];
    float m_run = -INFINITY, l_run = 0.f;
    f32x4 accO[4];
    #pragma unroll
    for (int t = 0; t < 4; ++t) accO[t] = (f32x4){0.f, 0.f, 0.f, 0.f};

    for (int kv = 0; kv < 8; ++kv) {
        const int k0s = kv * 64;
        const short* krs = kr + (bh + k0s) * ND;
        const short* kps = kp + (bh + k0s) * ND;
        const short* vts = vt + ((size_t)b * NH + h) * ND * NS + k0s;
        __syncthreads();    // previous iter (or Q frags) done with shared tiles
        #pragma unroll
        for (int p = 0; p < 2; ++p) {
            int u = tid + p * 256;
            int row = u >> 3, slot = u & 7;
            int off = (u * 16) ^ ((row & 7) << 4);
            *(bf16x8*)((char*)Kr_s + off) = *(const bf16x8*)(krs + u * 8);
            *(bf16x8*)((char*)Kp_s + off) = *(const bf16x8*)(kps + u * 8);
            *(bf16x8*)((char*)Vt_s + off) = *(const bf16x8*)(vts + (size_t)row * NS + slot * 8);
        }
        if (tid < 64) {
            int idx = b * NS + k0s + tid;
            ck_s[tid] = chain[idx];
            int ok = m_u8 ? (int)((const unsigned char*)amask)[idx] : ((const int*)amask)[idx];
            kb_s[tid] = ok ? 0.f : -INFINITY;
        }
        __syncthreads();

        // ---- scores: S = mfma(K, Q) -> D[key][q], lane: q=l15, key=t*16+g*4+r ----
        f32x4 sr[4], sp[4];
        #pragma unroll
        for (int t = 0; t < 4; ++t) { sr[t] = (f32x4){0.f,0.f,0.f,0.f}; sp[t] = (f32x4){0.f,0.f,0.f,0.f}; }
        #pragma unroll
        for (int h2 = 0; h2 < 2; ++h2) {
            const int cb = h2 * 64 + g * 16;
            #pragma unroll
            for (int t = 0; t < 4; ++t) {
                bf16x8 akr = lds_rd8(Kr_s, t * 16 + l15, cb);
                sr[t] = MFMA16(akr, fqr[h2], sr[t]);
                bf16x8 akp = lds_rd8(Kp_s, t * 16 + l15, cb);
                sp[t] = MFMA16(akp, fqp[h2], sp[t]);
            }
        }

        // ---- select + mask + online softmax (lane-local 16 keys + 2 shfl) ----
        float pm[4][4];
        float tmax = -INFINITY;
        #pragma unroll
        for (int t = 0; t < 4; ++t) {
            int4   ck4 = *(const int4*)&ck_s[t * 16 + g * 4];
            float4 kb4 = *(const float4*)&kb_s[t * 16 + g * 4];
            const int   ckk[4] = {ck4.x, ck4.y, ck4.z, ck4.w};
            const float kbb[4] = {kb4.x, kb4.y, kb4.z, kb4.w};
            #pragma unroll
            for (int r = 0; r < 4; ++r) {
                float sv = (cqv == ckk[r]) ? sp[t][r] : sr[t][r];
                sv = sv * 0.125f + kbb[r];
                pm[t][r] = sv;
                tmax = fmaxf(tmax, sv);
            }
        }
        tmax = fmaxf(tmax, __shfl_xor(tmax, 16));
        tmax = fmaxf(tmax, __shfl_xor(tmax, 32));
        float mnew = fmaxf(m_run, tmax);
        float fac, psum = 0.f;
        if (mnew == -INFINITY) {
            fac = 1.f;
            #pragma unroll
            for (int t = 0; t < 4; ++t)
                #pragma unroll
                for (int r = 0; r < 4; ++r) pm[t][r] = 0.f;
        } else {
            fac = __expf(m_run - mnew);
            #pragma unroll
            for (int t = 0; t < 4; ++t)
                #pragma unroll
                for (int r = 0; r < 4; ++r) {
                    float p = __expf(pm[t][r] - mnew);
                    pm[t][r] = p;
                    psum += p;
                }
        }
        psum += __shfl_xor(psum, 16);
        psum += __shfl_xor(psum, 32);
        l_run = l_run * fac + psum;
        m_run = mnew;

        // ---- write P (bf16) to wave-private swizzled LDS ----
        char* pb = (char*)P_s + wave * 2048;
        #pragma unroll
        for (int t = 0; t < 4; ++t) {
            bf16x4 pk = { f2bf(pm[t][0]), f2bf(pm[t][1]), f2bf(pm[t][2]), f2bf(pm[t][3]) };
            int off = (l15 * 128 + t * 32 + g * 8) ^ ((l15 & 7) << 4);
            *(bf16x4*)(pb + off) = pk;
        }
        // rescale accO by fac of row q=g*4+r (fac lives at lane q for q<16)
        float f4[4];
        #pragma unroll
        for (int r = 0; r < 4; ++r) f4[r] = __shfl(fac, g * 4 + r);
        #pragma unroll
        for (int t = 0; t < 4; ++t) {
            f32x4 a = accO[t];
            a[0] *= f4[0]; a[1] *= f4[1]; a[2] *= f4[2]; a[3] *= f4[3];
            accO[t] = a;
        }
        // ---- PV: out += mfma(P, V) ----
        bf16x8 pa[2];
        #pragma unroll
        for (int h2 = 0; h2 < 2; ++h2)
            pa[h2] = *(const bf16x8*)(pb + ((l15 * 128 + h2 * 64 + g * 16) ^ ((l15 & 7) << 4)));
        #pragma unroll
        for (int dt = 0; dt < 4; ++dt) {
            #pragma unroll
            for (int h2 = 0; h2 < 2; ++h2) {
                bf16x8 vb8 = lds_rd8(Vt_s, dt * 16 + l15, h2 * 64 + g * 16);
                accO[dt] = MFMA16(pa[h2], vb8, accO[dt]);
            }
        }
    }

    // ---- finalize: /l, nan_to_num, store bf16 ----
    float inv[4];
    #pragma unroll
    for (int r = 0; r < 4; ++r) {
        float lv = __shfl(l_run, g * 4 + r);
        inv[r] = (lv > 0.f) ? 1.f / lv : 0.f;
    }
    #pragma unroll
    for (int dt = 0; dt < 4; ++dt)
        #pragma unroll
        for (int r = 0; r < 4; ++r) {
            int row = b * NS + q0 + wave * 16 + g * 4 + r;
            aout[(size_t)row * NF + h * ND + dt * 16 + l15] = f2bf(accO[dt][r] * inv[r]);
        }
}

// ---------------- K7: output projection GEMM (bf16 MFMA, fp32 out) ----------------
__global__ __launch_bounds__(256) void gemm_out_kernel(const short* __restrict__ A,
    const short* __restrict__ Wot, float* __restrict__ out) {
    const int n0 = blockIdx.x * 128, m0 = blockIdx.y * 128;
    __shared__ short As[128 * 64], Bs[128 * 64];
    const int tid = threadIdx.x, lane = tid & 63, wave = tid >> 6;
    const int g = lane >> 4, l15 = lane & 15;
    const int wm = wave >> 1, wn = wave & 1;
    f32x4 acc[4][4];
    #pragma unroll
    for (int i = 0; i < 4; ++i)
        #pragma unroll
        for (int j = 0; j < 4; ++j) acc[i][j] = (f32x4){0.f, 0.f, 0.f, 0.f};

    for (int kt = 0; kt < 12; ++kt) {
        __syncthreads();
        const short* Asrc = A   + (size_t)m0 * 768 + kt * 64;
        const short* Bsrc = Wot + (size_t)n0 * 768 + kt * 64;
        #pragma unroll
        for (int p = 0; p < 4; ++p) {
            int u = tid + p * 256;
            int row = u >> 3, slot = u & 7;
            int off = (row * 128 + slot * 16) ^ ((row & 7) << 4);
            *(bf16x8*)((char*)As + off) = *(const bf16x8*)(Asrc + (size_t)row * 768 + slot * 8);
            *(bf16x8*)((char*)Bs + off) = *(const bf16x8*)(Bsrc + (size_t)row * 768 + slot * 8);
        }
        __syncthreads();
        #pragma unroll
        for (int h2 = 0; h2 < 2; ++h2) {
            bf16x8 af[4], bfr[4];
            const int cb = h2 * 64 + g * 16;
            #pragma unroll
            for (int i = 0; i < 4; ++i) {
                af[i]  = lds_rd8(As, wm * 64 + i * 16 + l15, cb);
                bfr[i] = lds_rd8(Bs, wn * 64 + i * 16 + l15, cb);
            }
            #pragma unroll
            for (int i = 0; i < 4; ++i)
                #pragma unroll
                for (int j = 0; j < 4; ++j)
                    acc[i][j] = MFMA16(af[i], bfr[j], acc[i][j]);
        }
    }
    #pragma unroll
    for (int i = 0; i < 4; ++i)
        #pragma unroll
        for (int r = 0; r < 4; ++r) {
            int m = m0 + wm * 64 + i * 16 + g * 4 + r;
            #pragma unroll
            for (int j = 0; j < 4; ++j) {
                int n = n0 + wn * 64 + j * 16 + l15;
                out[(size_t)m * NE + n] = acc[i][j][r];
            }
        }
}

extern "C" void kernel_launch(void* const* d_in, const int* in_sizes, int n_in,
                              void* d_out, int out_size, void* d_ws, size_t ws_size,
                              hipStream_t stream) {
    const float* x     = (const float*)d_in[0];
    const int*   chain = (const int*)d_in[1];
    const void*  amask = d_in[2];
    const float* Wq = (const float*)d_in[3];
    const float* Wk = (const float*)d_in[4];
    const float* Wv = (const float*)d_in[5];
    const float* Wo = (const float*)d_in[6];
    float* out = (float*)d_out;

    const size_t QSZ = (size_t)NB * NH * NS * ND;   // 6.29M elems
    char* w = (char*)d_ws;
    float* cos_t = (float*)w;  w += (size_t)NS * 32 * 4;
    float* sin_t = (float*)w;  w += (size_t)NS * 32 * 4;
    int*   mflag = (int*)w;    w += 256;
    short* xb    = (short*)w;  w += (size_t)8192 * 768 * 2;  // reused as aout later
    short* Wqt   = (short*)w;  w += (size_t)768 * 768 * 2;
    short* Wkt   = (short*)w;  w += (size_t)768 * 768 * 2;
    short* Wvt   = (short*)w;  w += (size_t)768 * 768 * 2;
    short* Wot   = (short*)w;  w += (size_t)768 * 768 * 2;
    short* q_raw = (short*)w;  w += QSZ * 2;
    short* k_raw = (short*)w;  w += QSZ * 2;
    short* v_nat = (short*)w;  w += QSZ * 2;
    short* q_rop = (short*)w;  w += QSZ * 2;
    short* k_rop = (short*)w;  w += QSZ * 2;
    short* vtr   = (short*)w;  w += QSZ * 2;
    short* aout  = xb;   // lifetime-disjoint reuse

    mask_probe_kernel<<<dim3(1), dim3(256), 0, stream>>>((const unsigned char*)amask, mflag);
    rope_table_kernel<<<dim3(64), dim3(256), 0, stream>>>(cos_t, sin_t);
    convert_x_kernel<<<dim3(3072), dim3(256), 0, stream>>>(x, xb);
    convert_wt_kernel<<<dim3(12, 12, 4), dim3(256), 0, stream>>>(Wq, Wk, Wv, Wo, Wqt, Wkt, Wvt, Wot);
    gemm_qkv_kernel<<<dim3(6, 64, 3), dim3(256), 0, stream>>>(xb, Wqt, Wkt, Wvt, q_raw, k_raw, v_nat);
    rope_tr_kernel<<<dim3(8, 12, 16), dim3(256), 0, stream>>>(q_raw, k_raw, v_nat, cos_t, sin_t,
                                                              q_rop, k_rop, vtr);
    attn_mfma_kernel<<<dim3(8, 12, 16), dim3(256), 0, stream>>>(q_raw, q_rop, k_raw, k_rop, vtr,
                                                                chain, amask, mflag, aout);
    gemm_out_kernel<<<dim3(6, 64), dim3(256), 0, stream>>>(aout, Wot, out);
}

// Round 4
// 164.625 us; speedup vs baseline: 6.4811x; 1.0952x over previous
//
#include <hip/hip_runtime.h>
#include <stdint.h>
#include <math.h>

#define NB 16
#define NS 512
#define NH 12
#define ND 64
#define NE 768
#define NF 768

typedef __attribute__((ext_vector_type(4))) float  f32x4;
typedef __attribute__((ext_vector_type(8))) short  bf16x8;
typedef __attribute__((ext_vector_type(4))) short  bf16x4;

__device__ __forceinline__ short f2bf(float f) {
    unsigned u = __builtin_bit_cast(unsigned, f);
    u += 0x7FFFu + ((u >> 16) & 1u);
    return (short)(u >> 16);
}
__device__ __forceinline__ float bf2f(short s) {
    unsigned u = ((unsigned)(unsigned short)s) << 16;
    return __builtin_bit_cast(float, u);
}

#define MFMA16(a, b, c) __builtin_amdgcn_mfma_f32_16x16x32_bf16((a), (b), (c), 0, 0, 0)

// swizzled LDS tile access: tiles are [rows][64] bf16 (128 B rows), byte ^= ((row&7)<<4)
__device__ __forceinline__ bf16x8 lds_rd8(const short* base, int row, int cb) {
    return *(const bf16x8*)((const char*)base + (((row) * 128 + (cb)) ^ (((row) & 7) << 4)));
}

// ---------------- K0: probe attention_mask storage dtype ----------------
__global__ __launch_bounds__(256) void mask_probe_kernel(const unsigned char* __restrict__ m,
                                                         int* __restrict__ flag) {
    __shared__ int any;
    if (threadIdx.x == 0) any = 0;
    __syncthreads();
    int acc = 0;
    for (int i = threadIdx.x; i < NB * NS; i += 256) {
        if ((i & 3) && m[i]) acc = 1;
    }
    if (acc) atomicOr(&any, 1);
    __syncthreads();
    if (threadIdx.x == 0) *flag = any;   // 1 = byte storage, 0 = int32 storage
}

// ---------------- K1: rope tables (fp32) ----------------
__global__ __launch_bounds__(256) void rope_table_kernel(float* __restrict__ cos_t,
                                                         float* __restrict__ sin_t) {
    int i = blockIdx.x * 256 + threadIdx.x;
    if (i >= NS * 32) return;
    int p = i >> 5;
    int j = i & 31;
    float inv_freq = powf(10000.0f, -(float)j / 32.0f);
    float ang = (float)p * inv_freq;
    cos_t[i] = cosf(ang);
    sin_t[i] = sinf(ang);
}

// ---------------- K2: convert x fp32 -> bf16 ----------------
__global__ __launch_bounds__(256) void convert_x_kernel(const float* __restrict__ x,
                                                        short* __restrict__ xb) {
    int i = (blockIdx.x * 256 + threadIdx.x) * 8;
    if (i >= 8192 * 768) return;
    float4 a = *(const float4*)&x[i];
    float4 b = *(const float4*)&x[i + 4];
    bf16x8 r = { f2bf(a.x), f2bf(a.y), f2bf(a.z), f2bf(a.w),
                 f2bf(b.x), f2bf(b.y), f2bf(b.z), f2bf(b.w) };
    *(bf16x8*)&xb[i] = r;
}

// ---------------- K3: transpose + convert weights: W[k][n] fp32 -> Wt[n][k] bf16 ----------------
__global__ __launch_bounds__(256) void convert_wt_kernel(
    const float* __restrict__ Wq, const float* __restrict__ Wk,
    const float* __restrict__ Wv, const float* __restrict__ Wo,
    short* __restrict__ Wqt, short* __restrict__ Wkt,
    short* __restrict__ Wvt, short* __restrict__ Wot) {
    const float* W  = (blockIdx.z == 0) ? Wq  : (blockIdx.z == 1) ? Wk  : (blockIdx.z == 2) ? Wv  : Wo;
    short*       Wt = (blockIdx.z == 0) ? Wqt : (blockIdx.z == 1) ? Wkt : (blockIdx.z == 2) ? Wvt : Wot;
    const int k0 = blockIdx.y * 64, n0 = blockIdx.x * 64;
    __shared__ float t[64][65];
    for (int u = threadIdx.x; u < 4096; u += 256) {
        int r = u >> 6, c = u & 63;
        t[r][c] = W[(size_t)(k0 + r) * 768 + n0 + c];
    }
    __syncthreads();
    for (int u = threadIdx.x; u < 4096; u += 256) {
        int c = u >> 6, r = u & 63;
        Wt[(size_t)(n0 + c) * 768 + k0 + r] = f2bf(t[r][c]);
    }
}

// ---------------- K4: QKV projection GEMM (bf16 MFMA) ----------------
__global__ __launch_bounds__(256) void gemm_qkv_kernel(const short* __restrict__ xb,
    const short* __restrict__ Wqt, const short* __restrict__ Wkt, const short* __restrict__ Wvt,
    short* __restrict__ qo, short* __restrict__ ko, short* __restrict__ vo) {
    const int z = blockIdx.z;
    const short* Bt = (z == 0) ? Wqt : (z == 1) ? Wkt : Wvt;
    short*       O  = (z == 0) ? qo  : (z == 1) ? ko  : vo;
    const int n0 = blockIdx.x * 128, m0 = blockIdx.y * 128;
    __shared__ short As[128 * 64], Bs[128 * 64];
    const int tid = threadIdx.x, lane = tid & 63, wave = tid >> 6;
    const int g = lane >> 4, l15 = lane & 15;
    const int wm = wave >> 1, wn = wave & 1;
    f32x4 acc[4][4];
    #pragma unroll
    for (int i = 0; i < 4; ++i)
        #pragma unroll
        for (int j = 0; j < 4; ++j) acc[i][j] = (f32x4){0.f, 0.f, 0.f, 0.f};

    for (int kt = 0; kt < 12; ++kt) {
        __syncthreads();
        const short* Asrc = xb + (size_t)m0 * 768 + kt * 64;
        const short* Bsrc = Bt + (size_t)n0 * 768 + kt * 64;
        #pragma unroll
        for (int p = 0; p < 4; ++p) {
            int u = tid + p * 256;
            int row = u >> 3, slot = u & 7;
            int off = (row * 128 + slot * 16) ^ ((row & 7) << 4);
            *(bf16x8*)((char*)As + off) = *(const bf16x8*)(Asrc + (size_t)row * 768 + slot * 8);
            *(bf16x8*)((char*)Bs + off) = *(const bf16x8*)(Bsrc + (size_t)row * 768 + slot * 8);
        }
        __syncthreads();
        #pragma unroll
        for (int h2 = 0; h2 < 2; ++h2) {
            bf16x8 af[4], bfr[4];
            const int cb = h2 * 64 + g * 16;
            #pragma unroll
            for (int i = 0; i < 4; ++i) {
                af[i]  = lds_rd8(As, wm * 64 + i * 16 + l15, cb);
                bfr[i] = lds_rd8(Bs, wn * 64 + i * 16 + l15, cb);
            }
            #pragma unroll
            for (int i = 0; i < 4; ++i)
                #pragma unroll
                for (int j = 0; j < 4; ++j)
                    acc[i][j] = MFMA16(af[i], bfr[j], acc[i][j]);
        }
    }
    #pragma unroll
    for (int i = 0; i < 4; ++i)
        #pragma unroll
        for (int r = 0; r < 4; ++r) {
            int m = m0 + wm * 64 + i * 16 + g * 4 + r;
            int bb = m >> 9, ss = m & 511;
            #pragma unroll
            for (int j = 0; j < 4; ++j) {
                int n = n0 + wn * 64 + j * 16 + l15;
                int hh = n >> 6, dd = n & 63;
                O[(((size_t)bb * NH + hh) * NS + ss) * ND + dd] = f2bf(acc[i][j][r]);
            }
        }
}

// ---------------- K5: V transpose: (b,h,s,d) -> (b,h,d,s) ----------------
__global__ __launch_bounds__(256) void v_tr_kernel(const short* __restrict__ v,
                                                   short* __restrict__ vt) {
    const int b = blockIdx.z, h = blockIdx.y, s0 = blockIdx.x * 64;
    const size_t base = (((size_t)b * NH + h) * NS + s0) * ND;
    const int tid = threadIdx.x;
    __shared__ short tv[64 * 72];
    #pragma unroll
    for (int p = 0; p < 2; ++p) {
        int u = tid + p * 256;
        int s = u >> 3, d8 = (u & 7) * 8;
        bf16x8 vv = *(const bf16x8*)(v + base + s * 64 + d8);
        #pragma unroll
        for (int j = 0; j < 8; ++j) tv[(d8 + j) * 72 + s] = vv[j];
    }
    __syncthreads();
    const size_t vtb = ((size_t)b * NH + h) * ND * NS + s0;
    #pragma unroll
    for (int p = 0; p < 2; ++p) {
        int u = tid + p * 256;
        int d = u >> 3, s8 = (u & 7) * 8;
        bf16x8 o = *(const bf16x8*)&tv[d * 72 + s8];
        *(bf16x8*)(vt + vtb + (size_t)d * NS + s8) = o;
    }
}

// ---------------- K6: fused chain-aware flash attention (RoPE in-kernel) ----------------
// 768 blocks flat, XCD-swizzled; BQ=128 (4 blocks/bh), 4 waves x 32 q-rows.
__global__ __launch_bounds__(256) void attn_fused_kernel(
    const short* __restrict__ qr, const short* __restrict__ kr, const short* __restrict__ vt,
    const float* __restrict__ cos_t, const float* __restrict__ sin_t,
    const int* __restrict__ chain, const void* __restrict__ amask,
    const int* __restrict__ mflag, short* __restrict__ aout) {
    // XCD swizzle: all 4 q-tiles of a (b,h) land on the same XCD, adjacent in dispatch
    const int lid = blockIdx.x;
    const int xcd = lid & 7;
    const int idx = lid >> 3;            // 0..95
    const int qt  = idx & 3;
    const int bh  = xcd * 24 + (idx >> 2);   // 0..191
    const int b = bh / 12, h = bh - (bh / 12) * 12;
    const int q0 = qt * 128;

    __shared__ short SM[20480];          // Kr 4096 | Kp 4096 | Vt 4096 | P 8192 (shorts)
    short* Kr_s = SM;
    short* Kp_s = SM + 4096;
    short* Vt_s = SM + 8192;
    __shared__ __align__(16) int   ck_s[64];
    __shared__ __align__(16) float kb_s[64];

    const int tid = threadIdx.x, lane = tid & 63, wave = tid >> 6;
    const int g = lane >> 4, l15 = lane & 15;
    const int m_u8 = *mflag;
    const size_t bhNS = (size_t)bh * NS;
    char* pb = (char*)(SM + 12288) + wave * 4096;

    // ---- stage Q tile (128x64) into SM[0..8191], then frags + in-register RoPE ----
    const short* qrs = qr + (bhNS + q0) * ND;
    #pragma unroll
    for (int p = 0; p < 4; ++p) {
        int u = tid + p * 256;
        int row = u >> 3, slot = u & 7;
        int off = (row * 128 + slot * 16) ^ ((row & 7) << 4);
        *(bf16x8*)((char*)SM + off) = *(const bf16x8*)(qrs + row * 64 + slot * 8);
    }
    __syncthreads();
    bf16x8 fqr[2][2], fqp[2][2];
    int   cqv[2];
    #pragma unroll
    for (int qg = 0; qg < 2; ++qg) {
        int rrow = wave * 32 + qg * 16 + l15;
        fqr[qg][0] = lds_rd8(SM, rrow, g * 16);
        fqr[qg][1] = lds_rd8(SM, rrow, 64 + g * 16);
        int pos = q0 + rrow;
        float4 c0 = *(const float4*)&cos_t[pos * 32 + g * 8];
        float4 c1 = *(const float4*)&cos_t[pos * 32 + g * 8 + 4];
        float4 s0 = *(const float4*)&sin_t[pos * 32 + g * 8];
        float4 s1 = *(const float4*)&sin_t[pos * 32 + g * 8 + 4];
        float cc[8] = {c0.x, c0.y, c0.z, c0.w, c1.x, c1.y, c1.z, c1.w};
        float ss[8] = {s0.x, s0.y, s0.z, s0.w, s1.x, s1.y, s1.z, s1.w};
        #pragma unroll
        for (int j = 0; j < 8; ++j) {
            float t1 = bf2f(fqr[qg][0][j]), t2 = bf2f(fqr[qg][1][j]);
            fqp[qg][0][j] = f2bf(t1 * cc[j] - t2 * ss[j]);
            fqp[qg][1][j] = f2bf(t1 * ss[j] + t2 * cc[j]);
        }
        cqv[qg] = chain[b * NS + pos];
    }

    float m_run[2] = {-INFINITY, -INFINITY};
    float l_run[2] = {0.f, 0.f};
    f32x4 accO[2][4];
    #pragma unroll
    for (int qg = 0; qg < 2; ++qg)
        #pragma unroll
        for (int t = 0; t < 4; ++t) accO[qg][t] = (f32x4){0.f, 0.f, 0.f, 0.f};

    const short* krb = kr + bhNS * ND;
    const short* vtb = vt + bhNS * ND;   // (d, s) layout

    for (int kv = 0; kv < 8; ++kv) {
        const int k0s = kv * 64;
        __syncthreads();    // prior iter (or Q-frag phase) done with SM
        // ---- stage K tile with cooperative RoPE: raw -> Kr_s, roped -> Kp_s ----
        {
            int key = tid >> 2, d8 = (tid & 3) * 8;       // 64 keys x 4 slots (d 0..31)
            const short* krow = krb + (k0s + key) * 64;
            bf16x8 lo = *(const bf16x8*)(krow + d8);
            bf16x8 hi = *(const bf16x8*)(krow + 32 + d8);
            float4 c0 = *(const float4*)&cos_t[(k0s + key) * 32 + d8];
            float4 c1 = *(const float4*)&cos_t[(k0s + key) * 32 + d8 + 4];
            float4 s0 = *(const float4*)&sin_t[(k0s + key) * 32 + d8];
            float4 s1 = *(const float4*)&sin_t[(k0s + key) * 32 + d8 + 4];
            float cc[8] = {c0.x, c0.y, c0.z, c0.w, c1.x, c1.y, c1.z, c1.w};
            float ss[8] = {s0.x, s0.y, s0.z, s0.w, s1.x, s1.y, s1.z, s1.w};
            bf16x8 plo, phi;
            #pragma unroll
            for (int j = 0; j < 8; ++j) {
                float t1 = bf2f(lo[j]), t2 = bf2f(hi[j]);
                plo[j] = f2bf(t1 * cc[j] - t2 * ss[j]);
                phi[j] = f2bf(t1 * ss[j] + t2 * cc[j]);
            }
            int basebyte = key * 128 + d8 * 2;
            int sw = (key & 7) << 4;
            *(bf16x8*)((char*)Kr_s + ((basebyte) ^ sw))      = lo;
            *(bf16x8*)((char*)Kr_s + ((basebyte + 64) ^ sw)) = hi;
            *(bf16x8*)((char*)Kp_s + ((basebyte) ^ sw))      = plo;
            *(bf16x8*)((char*)Kp_s + ((basebyte + 64) ^ sw)) = phi;
        }
        // ---- stage V^T tile (64 d x 64 s) ----
        #pragma unroll
        for (int p = 0; p < 2; ++p) {
            int u = tid + p * 256;
            int d = u >> 3, s8 = (u & 7) * 8;
            bf16x8 vv = *(const bf16x8*)(vtb + (size_t)d * NS + k0s + s8);
            *(bf16x8*)((char*)Vt_s + ((d * 128 + s8 * 2) ^ ((d & 7) << 4))) = vv;
        }
        if (tid < 64) {
            int gidx = b * NS + k0s + tid;
            ck_s[tid] = chain[gidx];
            int ok = m_u8 ? (int)((const unsigned char*)amask)[gidx] : ((const int*)amask)[gidx];
            kb_s[tid] = ok ? 0.f : -INFINITY;
        }
        __syncthreads();

        // ---- scores (t-outer keeps register pressure low) ----
        float pm[2][4][4];
        float tmax[2] = {-INFINITY, -INFINITY};
        #pragma unroll
        for (int t = 0; t < 4; ++t) {
            bf16x8 akr0 = lds_rd8(Kr_s, t * 16 + l15, g * 16);
            bf16x8 akr1 = lds_rd8(Kr_s, t * 16 + l15, 64 + g * 16);
            bf16x8 akp0 = lds_rd8(Kp_s, t * 16 + l15, g * 16);
            bf16x8 akp1 = lds_rd8(Kp_s, t * 16 + l15, 64 + g * 16);
            int4   ck4 = *(const int4*)&ck_s[t * 16 + g * 4];
            float4 kb4 = *(const float4*)&kb_s[t * 16 + g * 4];
            const int   ckk[4] = {ck4.x, ck4.y, ck4.z, ck4.w};
            const float kbb[4] = {kb4.x, kb4.y, kb4.z, kb4.w};
            #pragma unroll
            for (int qg = 0; qg < 2; ++qg) {
                f32x4 sr = (f32x4){0.f, 0.f, 0.f, 0.f};
                f32x4 sp = (f32x4){0.f, 0.f, 0.f, 0.f};
                sr = MFMA16(akr0, fqr[qg][0], sr);
                sr = MFMA16(akr1, fqr[qg][1], sr);
                sp = MFMA16(akp0, fqp[qg][0], sp);
                sp = MFMA16(akp1, fqp[qg][1], sp);
                #pragma unroll
                for (int r = 0; r < 4; ++r) {
                    float sv = (cqv[qg] == ckk[r]) ? sp[r] : sr[r];
                    sv = sv * 0.125f + kbb[r];
                    pm[qg][t][r] = sv;
                    tmax[qg] = fmaxf(tmax[qg], sv);
                }
            }
        }

        // ---- per-qg online softmax + P write + rescale + PV ----
        #pragma unroll
        for (int qg = 0; qg < 2; ++qg) {
            float tm = tmax[qg];
            tm = fmaxf(tm, __shfl_xor(tm, 16));
            tm = fmaxf(tm, __shfl_xor(tm, 32));
            float mnew = fmaxf(m_run[qg], tm);
            float fac, psum = 0.f;
            if (mnew == -INFINITY) {
                fac = 1.f;
                #pragma unroll
                for (int t = 0; t < 4; ++t)
                    #pragma unroll
                    for (int r = 0; r < 4; ++r) pm[qg][t][r] = 0.f;
            } else {
                fac = __expf(m_run[qg] - mnew);
                #pragma unroll
                for (int t = 0; t < 4; ++t)
                    #pragma unroll
                    for (int r = 0; r < 4; ++r) {
                        float p = __expf(pm[qg][t][r] - mnew);
                        pm[qg][t][r] = p;
                        psum += p;
                    }
            }
            psum += __shfl_xor(psum, 16);
            psum += __shfl_xor(psum, 32);
            l_run[qg] = l_run[qg] * fac + psum;
            m_run[qg] = mnew;

            int prow = qg * 16 + l15;
            int psw = (prow & 7) << 4;
            #pragma unroll
            for (int t = 0; t < 4; ++t) {
                bf16x4 pk = { f2bf(pm[qg][t][0]), f2bf(pm[qg][t][1]),
                              f2bf(pm[qg][t][2]), f2bf(pm[qg][t][3]) };
                *(bf16x4*)(pb + ((prow * 128 + t * 32 + g * 8) ^ psw)) = pk;
            }
            float f4[4];
            #pragma unroll
            for (int r = 0; r < 4; ++r) f4[r] = __shfl(fac, g * 4 + r);
            #pragma unroll
            for (int t = 0; t < 4; ++t) {
                f32x4 a = accO[qg][t];
                a[0] *= f4[0]; a[1] *= f4[1]; a[2] *= f4[2]; a[3] *= f4[3];
                accO[qg][t] = a;
            }
            bf16x8 pa0 = *(const bf16x8*)(pb + ((prow * 128 + g * 16) ^ psw));
            bf16x8 pa1 = *(const bf16x8*)(pb + ((prow * 128 + 64 + g * 16) ^ psw));
            #pragma unroll
            for (int dt = 0; dt < 4; ++dt) {
                bf16x8 vb0 = lds_rd8(Vt_s, dt * 16 + l15, g * 16);
                bf16x8 vb1 = lds_rd8(Vt_s, dt * 16 + l15, 64 + g * 16);
                accO[qg][dt] = MFMA16(pa0, vb0, accO[qg][dt]);
                accO[qg][dt] = MFMA16(pa1, vb1, accO[qg][dt]);
            }
        }
    }

    // ---- finalize: /l, nan_to_num, store bf16 ----
    #pragma unroll
    for (int qg = 0; qg < 2; ++qg) {
        float inv[4];
        #pragma unroll
        for (int r = 0; r < 4; ++r) {
            float lv = __shfl(l_run[qg], g * 4 + r);
            inv[r] = (lv > 0.f) ? 1.f / lv : 0.f;
        }
        #pragma unroll
        for (int dt = 0; dt < 4; ++dt)
            #pragma unroll
            for (int r = 0; r < 4; ++r) {
                int row = b * NS + q0 + wave * 32 + qg * 16 + g * 4 + r;
                aout[(size_t)row * NF + h * ND + dt * 16 + l15] = f2bf(accO[qg][dt][r] * inv[r]);
            }
    }
}

// ---------------- K7: output projection GEMM (bf16 MFMA, fp32 out) ----------------
__global__ __launch_bounds__(256) void gemm_out_kernel(const short* __restrict__ A,
    const short* __restrict__ Wot, float* __restrict__ out) {
    const int n0 = blockIdx.x * 128, m0 = blockIdx.y * 128;
    __shared__ short As[128 * 64], Bs[128 * 64];
    const int tid = threadIdx.x, lane = tid & 63, wave = tid >> 6;
    const int g = lane >> 4, l15 = lane & 15;
    const int wm = wave >> 1, wn = wave & 1;
    f32x4 acc[4][4];
    #pragma unroll
    for (int i = 0; i < 4; ++i)
        #pragma unroll
        for (int j = 0; j < 4; ++j) acc[i][j] = (f32x4){0.f, 0.f, 0.f, 0.f};

    for (int kt = 0; kt < 12; ++kt) {
        __syncthreads();
        const short* Asrc = A   + (size_t)m0 * 768 + kt * 64;
        const short* Bsrc = Wot + (size_t)n0 * 768 + kt * 64;
        #pragma unroll
        for (int p = 0; p < 4; ++p) {
            int u = tid + p * 256;
            int row = u >> 3, slot = u & 7;
            int off = (row * 128 + slot * 16) ^ ((row & 7) << 4);
            *(bf16x8*)((char*)As + off) = *(const bf16x8*)(Asrc + (size_t)row * 768 + slot * 8);
            *(bf16x8*)((char*)Bs + off) = *(const bf16x8*)(Bsrc + (size_t)row * 768 + slot * 8);
        }
        __syncthreads();
        #pragma unroll
        for (int h2 = 0; h2 < 2; ++h2) {
            bf16x8 af[4], bfr[4];
            const int cb = h2 * 64 + g * 16;
            #pragma unroll
            for (int i = 0; i < 4; ++i) {
                af[i]  = lds_rd8(As, wm * 64 + i * 16 + l15, cb);
                bfr[i] = lds_rd8(Bs, wn * 64 + i * 16 + l15, cb);
            }
            #pragma unroll
            for (int i = 0; i < 4; ++i)
                #pragma unroll
                for (int j = 0; j < 4; ++j)
                    acc[i][j] = MFMA16(af[i], bfr[j], acc[i][j]);
        }
    }
    #pragma unroll
    for (int i = 0; i < 4; ++i)
        #pragma unroll
        for (int r = 0; r < 4; ++r) {
            int m = m0 + wm * 64 + i * 16 + g * 4 + r;
            #pragma unroll
            for (int j = 0; j < 4; ++j) {
                int n = n0 + wn * 64 + j * 16 + l15;
                out[(size_t)m * NE + n] = acc[i][j][r];
            }
        }
}

extern "C" void kernel_launch(void* const* d_in, const int* in_sizes, int n_in,
                              void* d_out, int out_size, void* d_ws, size_t ws_size,
                              hipStream_t stream) {
    const float* x     = (const float*)d_in[0];
    const int*   chain = (const int*)d_in[1];
    const void*  amask = d_in[2];
    const float* Wq = (const float*)d_in[3];
    const float* Wk = (const float*)d_in[4];
    const float* Wv = (const float*)d_in[5];
    const float* Wo = (const float*)d_in[6];
    float* out = (float*)d_out;

    const size_t QSZ = (size_t)NB * NH * NS * ND;
    char* w = (char*)d_ws;
    float* cos_t = (float*)w;  w += (size_t)NS * 32 * 4;
    float* sin_t = (float*)w;  w += (size_t)NS * 32 * 4;
    int*   mflag = (int*)w;    w += 256;
    short* xb    = (short*)w;  w += (size_t)8192 * 768 * 2;  // reused as aout later
    short* Wqt   = (short*)w;  w += (size_t)768 * 768 * 2;
    short* Wkt   = (short*)w;  w += (size_t)768 * 768 * 2;
    short* Wvt   = (short*)w;  w += (size_t)768 * 768 * 2;
    short* Wot   = (short*)w;  w += (size_t)768 * 768 * 2;
    short* q_raw = (short*)w;  w += QSZ * 2;
    short* k_raw = (short*)w;  w += QSZ * 2;
    short* v_nat = (short*)w;  w += QSZ * 2;
    short* vtr   = (short*)w;  w += QSZ * 2;
    short* aout  = xb;   // lifetime-disjoint reuse

    mask_probe_kernel<<<dim3(1), dim3(256), 0, stream>>>((const unsigned char*)amask, mflag);
    rope_table_kernel<<<dim3(64), dim3(256), 0, stream>>>(cos_t, sin_t);
    convert_x_kernel<<<dim3(3072), dim3(256), 0, stream>>>(x, xb);
    convert_wt_kernel<<<dim3(12, 12, 4), dim3(256), 0, stream>>>(Wq, Wk, Wv, Wo, Wqt, Wkt, Wvt, Wot);
    gemm_qkv_kernel<<<dim3(6, 64, 3), dim3(256), 0, stream>>>(xb, Wqt, Wkt, Wvt, q_raw, k_raw, v_nat);
    v_tr_kernel<<<dim3(8, 12, 16), dim3(256), 0, stream>>>(v_nat, vtr);
    attn_fused_kernel<<<dim3(768), dim3(256), 0, stream>>>(q_raw, k_raw, vtr, cos_t, sin_t,
                                                           chain, amask, mflag, aout);
    gemm_out_kernel<<<dim3(6, 64), dim3(256), 0, stream>>>(aout, Wot, out);
}

// Round 6
// 159.825 us; speedup vs baseline: 6.6758x; 1.0300x over previous
//
#include <hip/hip_runtime.h>
#include <stdint.h>
#include <math.h>

#define NB 16
#define NS 512
#define NH 12
#define ND 64
#define NE 768
#define NF 768

typedef __attribute__((ext_vector_type(4))) float  f32x4;
typedef __attribute__((ext_vector_type(8))) short  bf16x8;
typedef __attribute__((ext_vector_type(4))) short  bf16x4;

#define AS1(p) ((const __attribute__((address_space(1))) unsigned int*)(p))
#define AS3(p) ((__attribute__((address_space(3))) unsigned int*)(p))

__device__ __forceinline__ short f2bf(float f) {
    unsigned u = __builtin_bit_cast(unsigned, f);
    u += 0x7FFFu + ((u >> 16) & 1u);
    return (short)(u >> 16);
}
__device__ __forceinline__ float bf2f(short s) {
    unsigned u = ((unsigned)(unsigned short)s) << 16;
    return __builtin_bit_cast(float, u);
}
// packed pair f32->bf16 (RNE, same numerics as cvt_pk; compiler schedules fine)
__device__ __forceinline__ unsigned pkbf2(float a, float b) {
    return (unsigned)(unsigned short)f2bf(a) | ((unsigned)(unsigned short)f2bf(b) << 16);
}

#define MFMA16(a, b, c) __builtin_amdgcn_mfma_f32_16x16x32_bf16((a), (b), (c), 0, 0, 0)

// swizzled LDS tile access: tiles are [rows][64] bf16 (128 B rows), byte ^= ((row&7)<<4)
__device__ __forceinline__ bf16x8 lds_rd8(const short* base, int row, int cb) {
    return *(const bf16x8*)((const char*)base + (((row) * 128 + (cb)) ^ (((row) & 7) << 4)));
}

// ---------------- K1: rope tables + mask-dtype probe (merged) ----------------
__global__ __launch_bounds__(256) void prep_kernel(float* __restrict__ cos_t,
                                                   float* __restrict__ sin_t,
                                                   const unsigned char* __restrict__ m,
                                                   int* __restrict__ flag) {
    if (blockIdx.x == 64) {   // probe: byte storage has nonzero bytes at offsets %4 != 0
        __shared__ int any;
        if (threadIdx.x == 0) any = 0;
        __syncthreads();
        int acc = 0;
        for (int i = threadIdx.x; i < NB * NS; i += 256)
            if ((i & 3) && m[i]) acc = 1;
        if (acc) atomicOr(&any, 1);
        __syncthreads();
        if (threadIdx.x == 0) *flag = any;   // 1 = byte storage, 0 = int32 storage
        return;
    }
    int i = blockIdx.x * 256 + threadIdx.x;
    int p = i >> 5, j = i & 31;
    float inv_freq = powf(10000.0f, -(float)j / 32.0f);
    float ang = (float)p * inv_freq;
    cos_t[i] = cosf(ang);
    sin_t[i] = sinf(ang);
}

// ---------------- K2: convert x fp32 -> bf16 ----------------
__global__ __launch_bounds__(256) void convert_x_kernel(const float* __restrict__ x,
                                                        short* __restrict__ xb) {
    int i = (blockIdx.x * 256 + threadIdx.x) * 8;
    if (i >= 8192 * 768) return;
    float4 a = *(const float4*)&x[i];
    float4 b = *(const float4*)&x[i + 4];
    bf16x8 r = { f2bf(a.x), f2bf(a.y), f2bf(a.z), f2bf(a.w),
                 f2bf(b.x), f2bf(b.y), f2bf(b.z), f2bf(b.w) };
    *(bf16x8*)&xb[i] = r;
}

// ---------------- K3: transpose + convert weights: W[k][n] fp32 -> Wt[n][k] bf16 ----------------
__global__ __launch_bounds__(256) void convert_wt_kernel(
    const float* __restrict__ Wq, const float* __restrict__ Wk,
    const float* __restrict__ Wv, const float* __restrict__ Wo,
    short* __restrict__ Wqt, short* __restrict__ Wkt,
    short* __restrict__ Wvt, short* __restrict__ Wot) {
    const float* W  = (blockIdx.z == 0) ? Wq  : (blockIdx.z == 1) ? Wk  : (blockIdx.z == 2) ? Wv  : Wo;
    short*       Wt = (blockIdx.z == 0) ? Wqt : (blockIdx.z == 1) ? Wkt : (blockIdx.z == 2) ? Wvt : Wot;
    const int k0 = blockIdx.y * 64, n0 = blockIdx.x * 64;
    __shared__ float t[64][65];
    for (int u = threadIdx.x; u < 4096; u += 256) {
        int r = u >> 6, c = u & 63;
        t[r][c] = W[(size_t)(k0 + r) * 768 + n0 + c];
    }
    __syncthreads();
    for (int u = threadIdx.x; u < 4096; u += 256) {
        int c = u >> 6, r = u & 63;
        Wt[(size_t)(n0 + c) * 768 + k0 + r] = f2bf(t[r][c]);
    }
}

// ---------------- K4: QKV projection GEMM (bf16 MFMA, global_load_lds staging) ----------------
// z==2 (V) writes transposed (b,h,d,s) directly.
__global__ __launch_bounds__(256) void gemm_qkv_kernel(const short* __restrict__ xb,
    const short* __restrict__ Wqt, const short* __restrict__ Wkt, const short* __restrict__ Wvt,
    short* __restrict__ qo, short* __restrict__ ko, short* __restrict__ vto) {
    const int z = blockIdx.z;
    const short* Bt = (z == 0) ? Wqt : (z == 1) ? Wkt : Wvt;
    short*       O  = (z == 0) ? qo  : (z == 1) ? ko  : vto;
    const int n0 = blockIdx.x * 128, m0 = blockIdx.y * 128;
    __shared__ short As[128 * 64], Bs[128 * 64];
    const int tid = threadIdx.x, lane = tid & 63, wave = tid >> 6;
    const int g = lane >> 4, l15 = lane & 15;
    const int wm = wave >> 1, wn = wave & 1;
    f32x4 acc[4][4];
    #pragma unroll
    for (int i = 0; i < 4; ++i)
        #pragma unroll
        for (int j = 0; j < 4; ++j) acc[i][j] = (f32x4){0.f, 0.f, 0.f, 0.f};

    for (int kt = 0; kt < 12; ++kt) {
        __syncthreads();
        const char* Asrc = (const char*)(xb + (size_t)m0 * 768 + kt * 64);
        const char* Bsrc = (const char*)(Bt + (size_t)n0 * 768 + kt * 64);
        #pragma unroll
        for (int p = 0; p < 4; ++p) {
            int dstoff = (wave * 4 + p) * 1024;           // wave-uniform LDS base
            int off = dstoff + lane * 16;
            int row = off >> 7, slot = off & 127;
            int srcs = slot ^ ((row & 7) << 4);           // inverse-swizzled source
            __builtin_amdgcn_global_load_lds(AS1(Asrc + (size_t)row * 1536 + srcs),
                                             AS3((char*)As + dstoff), 16, 0, 0);
            __builtin_amdgcn_global_load_lds(AS1(Bsrc + (size_t)row * 1536 + srcs),
                                             AS3((char*)Bs + dstoff), 16, 0, 0);
        }
        __syncthreads();
        __builtin_amdgcn_s_setprio(1);
        #pragma unroll
        for (int h2 = 0; h2 < 2; ++h2) {
            bf16x8 af[4], bfr[4];
            const int cb = h2 * 64 + g * 16;
            #pragma unroll
            for (int i = 0; i < 4; ++i) {
                af[i]  = lds_rd8(As, wm * 64 + i * 16 + l15, cb);
                bfr[i] = lds_rd8(Bs, wn * 64 + i * 16 + l15, cb);
            }
            #pragma unroll
            for (int i = 0; i < 4; ++i)
                #pragma unroll
                for (int j = 0; j < 4; ++j)
                    acc[i][j] = MFMA16(af[i], bfr[j], acc[i][j]);
        }
        __builtin_amdgcn_s_setprio(0);
    }
    #pragma unroll
    for (int i = 0; i < 4; ++i)
        #pragma unroll
        for (int r = 0; r < 4; ++r) {
            int mm = m0 + wm * 64 + i * 16 + g * 4 + r;
            int bb = mm >> 9, ss = mm & 511;
            #pragma unroll
            for (int j = 0; j < 4; ++j) {
                int n = n0 + wn * 64 + j * 16 + l15;
                int hh = n >> 6, dd = n & 63;
                short val = f2bf(acc[i][j][r]);
                if (z == 2)  // V: (b,h,d,s)
                    O[(((size_t)bb * NH + hh) * ND + dd) * NS + ss] = val;
                else         // Q,K: (b,h,s,d)
                    O[(((size_t)bb * NH + hh) * NS + ss) * ND + dd] = val;
            }
        }
}

// ---------------- K6: fused chain-aware flash attention ----------------
// grid 1536 flat, XCD-swizzled: 8 q-tiles (BQ=64) of a (b,h) adjacent on one XCD.
// 4 waves x 16 q-rows. LDS 24.5 KB -> 6 blocks/CU. P overlays Kr_s after scores.
__global__ __launch_bounds__(256) void attn_fused_kernel(
    const short* __restrict__ qr, const short* __restrict__ kr, const short* __restrict__ vt,
    const float* __restrict__ cos_t, const float* __restrict__ sin_t,
    const int* __restrict__ chain, const void* __restrict__ amask,
    const int* __restrict__ mflag, short* __restrict__ aout) {
    const int lid = blockIdx.x;
    const int xcd = lid & 7, idx = lid >> 3;
    const int qt = idx & 7, bhl = idx >> 3;
    const int bh = xcd * 24 + bhl;
    const int b = bh / 12, h = bh - (bh / 12) * 12;
    const int q0 = qt * 64;

    __shared__ short Kr_s[4096];   // K raw tile; after scores: P (4 waves x 2 KB)
    __shared__ short Kp_s[4096];   // K roped tile
    __shared__ short Vt_s[4096];   // V^T tile [d][s]
    __shared__ __align__(16) int   ck_s[64];
    __shared__ __align__(16) float kb_s[64];

    const int tid = threadIdx.x, lane = tid & 63, wave = tid >> 6;
    const int g = lane >> 4, l15 = lane & 15;
    const int m_u8 = *mflag;
    const size_t bhNS = (size_t)bh * NS;
    const float SC = 0.18033688011f;   // 0.125 * log2(e): softmax in exp2 domain

    // ---- stage Q tile (64x64) into Kr_s temp, extract frags, in-register RoPE ----
    const short* qrs = qr + (bhNS + q0) * ND;
    #pragma unroll
    for (int p = 0; p < 2; ++p) {
        int u = tid + p * 256;
        int row = u >> 3, slot = u & 7;
        int off = (row * 128 + slot * 16) ^ ((row & 7) << 4);
        *(bf16x8*)((char*)Kr_s + off) = *(const bf16x8*)(qrs + row * 64 + slot * 8);
    }
    __syncthreads();
    const int qrow = wave * 16 + l15;
    bf16x8 fqr0 = lds_rd8(Kr_s, qrow, g * 16);
    bf16x8 fqr1 = lds_rd8(Kr_s, qrow, 64 + g * 16);
    bf16x8 fqp0, fqp1;
    {
        int pos = q0 + qrow;
        float4 c0 = *(const float4*)&cos_t[pos * 32 + g * 8];
        float4 c1 = *(const float4*)&cos_t[pos * 32 + g * 8 + 4];
        float4 s0 = *(const float4*)&sin_t[pos * 32 + g * 8];
        float4 s1 = *(const float4*)&sin_t[pos * 32 + g * 8 + 4];
        float cc[8] = {c0.x, c0.y, c0.z, c0.w, c1.x, c1.y, c1.z, c1.w};
        float ss[8] = {s0.x, s0.y, s0.z, s0.w, s1.x, s1.y, s1.z, s1.w};
        #pragma unroll
        for (int j = 0; j < 8; ++j) {
            float t1 = bf2f(fqr0[j]), t2 = bf2f(fqr1[j]);
            fqp0[j] = f2bf(t1 * cc[j] - t2 * ss[j]);
            fqp1[j] = f2bf(t1 * ss[j] + t2 * cc[j]);
        }
    }
    const int cqv = chain[b * NS + q0 + qrow];

    float m_run = -INFINITY, l_run = 0.f;
    f32x4 accO[4];
    #pragma unroll
    for (int t = 0; t < 4; ++t) accO[t] = (f32x4){0.f, 0.f, 0.f, 0.f};

    const short* krb = kr + bhNS * ND;
    const char*  vtb = (const char*)(vt + bhNS * ND);   // (d,s) layout, row stride 1024 B

    for (int kv = 0; kv < 8; ++kv) {
        const int k0s = kv * 64;
        __syncthreads();   // prev PV (and Q-frag reads) done -> restage
        // ---- stage K with cooperative RoPE ----
        {
            int key = tid >> 2, d8 = (tid & 3) * 8;
            const short* krow = krb + (k0s + key) * 64;
            bf16x8 lo = *(const bf16x8*)(krow + d8);
            bf16x8 hi = *(const bf16x8*)(krow + 32 + d8);
            float4 c0 = *(const float4*)&cos_t[(k0s + key) * 32 + d8];
            float4 c1 = *(const float4*)&cos_t[(k0s + key) * 32 + d8 + 4];
            float4 s0 = *(const float4*)&sin_t[(k0s + key) * 32 + d8];
            float4 s1 = *(const float4*)&sin_t[(k0s + key) * 32 + d8 + 4];
            float cc[8] = {c0.x, c0.y, c0.z, c0.w, c1.x, c1.y, c1.z, c1.w};
            float ss[8] = {s0.x, s0.y, s0.z, s0.w, s1.x, s1.y, s1.z, s1.w};
            bf16x8 plo, phi;
            #pragma unroll
            for (int j = 0; j < 8; ++j) {
                float t1 = bf2f(lo[j]), t2 = bf2f(hi[j]);
                plo[j] = f2bf(t1 * cc[j] - t2 * ss[j]);
                phi[j] = f2bf(t1 * ss[j] + t2 * cc[j]);
            }
            int basebyte = key * 128 + d8 * 2;
            int sw = (key & 7) << 4;
            *(bf16x8*)((char*)Kr_s + ((basebyte) ^ sw))      = lo;
            *(bf16x8*)((char*)Kr_s + ((basebyte + 64) ^ sw)) = hi;
            *(bf16x8*)((char*)Kp_s + ((basebyte) ^ sw))      = plo;
            *(bf16x8*)((char*)Kp_s + ((basebyte + 64) ^ sw)) = phi;
        }
        // ---- stage V^T via global_load_lds (linear dest, inverse-swizzled source) ----
        #pragma unroll
        for (int p = 0; p < 2; ++p) {
            int dstoff = (wave * 2 + p) * 1024;           // wave-uniform
            int off = dstoff + lane * 16;
            int d = off >> 7, slot = off & 127;
            int srcs = slot ^ ((d & 7) << 4);
            __builtin_amdgcn_global_load_lds(AS1(vtb + (size_t)d * 1024 + k0s * 2 + srcs),
                                             AS3((char*)Vt_s + dstoff), 16, 0, 0);
        }
        if (tid < 64) {
            int gidx = b * NS + k0s + tid;
            ck_s[tid] = chain[gidx];
            int ok = m_u8 ? (int)((const unsigned char*)amask)[gidx] : ((const int*)amask)[gidx];
            kb_s[tid] = ok ? 0.f : -INFINITY;
        }
        __syncthreads();

        // ---- scores: S = mfma(K, Q): lane holds 16 keys (t,r) for q-row l15 ----
        float pm[4][4];
        float tm = -INFINITY;
        __builtin_amdgcn_s_setprio(1);
        #pragma unroll
        for (int t = 0; t < 4; ++t) {
            bf16x8 akr0 = lds_rd8(Kr_s, t * 16 + l15, g * 16);
            bf16x8 akr1 = lds_rd8(Kr_s, t * 16 + l15, 64 + g * 16);
            bf16x8 akp0 = lds_rd8(Kp_s, t * 16 + l15, g * 16);
            bf16x8 akp1 = lds_rd8(Kp_s, t * 16 + l15, 64 + g * 16);
            f32x4 sr = (f32x4){0.f, 0.f, 0.f, 0.f};
            f32x4 sp = (f32x4){0.f, 0.f, 0.f, 0.f};
            sr = MFMA16(akr0, fqr0, sr);
            sr = MFMA16(akr1, fqr1, sr);
            sp = MFMA16(akp0, fqp0, sp);
            sp = MFMA16(akp1, fqp1, sp);
            int4   ck4 = *(const int4*)&ck_s[t * 16 + g * 4];
            float4 kb4 = *(const float4*)&kb_s[t * 16 + g * 4];
            const int   ckk[4] = {ck4.x, ck4.y, ck4.z, ck4.w};
            const float kbb[4] = {kb4.x, kb4.y, kb4.z, kb4.w};
            #pragma unroll
            for (int r = 0; r < 4; ++r) {
                float sv = (cqv == ckk[r]) ? sp[r] : sr[r];
                sv = sv * SC + kbb[r];
                pm[t][r] = sv;
                tm = fmaxf(tm, sv);
            }
        }
        __builtin_amdgcn_s_setprio(0);
        __syncthreads();   // all waves done reading Kr/Kp -> P may overlay Kr_s

        // ---- online softmax (exp2 domain) with defer-max ----
        tm = fmaxf(tm, __shfl_xor(tm, 16));
        tm = fmaxf(tm, __shfl_xor(tm, 32));
        bool skip = __all(tm - m_run <= 8.f);   // NaN(inf-inf) -> false -> normal path
        float mnew, fac;
        if (skip) { mnew = m_run; fac = 1.f; }
        else      { mnew = fmaxf(m_run, tm); fac = exp2f(m_run - mnew); }
        float psum = 0.f;
        if (mnew == -INFINITY) {
            #pragma unroll
            for (int t = 0; t < 4; ++t)
                #pragma unroll
                for (int r = 0; r < 4; ++r) pm[t][r] = 0.f;
            fac = 1.f;
        } else {
            #pragma unroll
            for (int t = 0; t < 4; ++t)
                #pragma unroll
                for (int r = 0; r < 4; ++r) {
                    float p = exp2f(pm[t][r] - mnew);
                    pm[t][r] = p;
                    psum += p;
                }
        }
        psum += __shfl_xor(psum, 16);
        psum += __shfl_xor(psum, 32);
        l_run = l_run * fac + psum;
        m_run = mnew;

        // ---- P -> bf16 into wave-private overlay region (Kr_s + wave*2 KB) ----
        char* pwave = (char*)Kr_s + wave * 2048;
        int psw = (l15 & 7) << 4;
        #pragma unroll
        for (int t = 0; t < 4; ++t) {
            unsigned u0 = pkbf2(pm[t][0], pm[t][1]);
            unsigned u1 = pkbf2(pm[t][2], pm[t][3]);
            uint2 pk = {u0, u1};
            *(uint2*)(pwave + ((l15 * 128 + t * 32 + g * 8) ^ psw)) = pk;
        }
        if (!skip) {
            float f4[4];
            #pragma unroll
            for (int r = 0; r < 4; ++r) f4[r] = __shfl(fac, g * 4 + r);
            #pragma unroll
            for (int t = 0; t < 4; ++t) {
                f32x4 a = accO[t];
                a[0] *= f4[0]; a[1] *= f4[1]; a[2] *= f4[2]; a[3] *= f4[3];
                accO[t] = a;
            }
        }
        // ---- PV: accO += mfma(P, V) ----
        bf16x8 pa0 = *(const bf16x8*)(pwave + ((l15 * 128 + g * 16) ^ psw));
        bf16x8 pa1 = *(const bf16x8*)(pwave + ((l15 * 128 + 64 + g * 16) ^ psw));
        __builtin_amdgcn_s_setprio(1);
        #pragma unroll
        for (int dt = 0; dt < 4; ++dt) {
            bf16x8 vb0 = lds_rd8(Vt_s, dt * 16 + l15, g * 16);
            bf16x8 vb1 = lds_rd8(Vt_s, dt * 16 + l15, 64 + g * 16);
            accO[dt] = MFMA16(pa0, vb0, accO[dt]);
            accO[dt] = MFMA16(pa1, vb1, accO[dt]);
        }
        __builtin_amdgcn_s_setprio(0);
    }

    // ---- finalize: /l, nan_to_num, store bf16 ----
    float inv[4];
    #pragma unroll
    for (int r = 0; r < 4; ++r) {
        float lv = __shfl(l_run, g * 4 + r);
        inv[r] = (lv > 0.f) ? 1.f / lv : 0.f;
    }
    #pragma unroll
    for (int dt = 0; dt < 4; ++dt)
        #pragma unroll
        for (int r = 0; r < 4; ++r) {
            int row = b * NS + q0 + wave * 16 + g * 4 + r;
            aout[(size_t)row * NF + h * ND + dt * 16 + l15] = f2bf(accO[dt][r] * inv[r]);
        }
}

// ---------------- K7: output projection GEMM (64x128 tiles, glds staging) ----------------
__global__ __launch_bounds__(256) void gemm_out_kernel(const short* __restrict__ A,
    const short* __restrict__ Wot, float* __restrict__ out) {
    const int n0 = blockIdx.x * 128, m0 = blockIdx.y * 64;
    __shared__ short As[64 * 64], Bs[128 * 64];
    const int tid = threadIdx.x, lane = tid & 63, wave = tid >> 6;
    const int g = lane >> 4, l15 = lane & 15;
    const int wm = wave >> 1, wn = wave & 1;
    f32x4 acc[2][4];
    #pragma unroll
    for (int i = 0; i < 2; ++i)
        #pragma unroll
        for (int j = 0; j < 4; ++j) acc[i][j] = (f32x4){0.f, 0.f, 0.f, 0.f};

    for (int kt = 0; kt < 12; ++kt) {
        __syncthreads();
        const char* Asrc = (const char*)(A   + (size_t)m0 * 768 + kt * 64);
        const char* Bsrc = (const char*)(Wot + (size_t)n0 * 768 + kt * 64);
        #pragma unroll
        for (int p = 0; p < 2; ++p) {
            int dstoff = (wave * 2 + p) * 1024;
            int off = dstoff + lane * 16;
            int row = off >> 7, slot = off & 127;
            int srcs = slot ^ ((row & 7) << 4);
            __builtin_amdgcn_global_load_lds(AS1(Asrc + (size_t)row * 1536 + srcs),
                                             AS3((char*)As + dstoff), 16, 0, 0);
        }
        #pragma unroll
        for (int p = 0; p < 4; ++p) {
            int dstoff = (wave * 4 + p) * 1024;
            int off = dstoff + lane * 16;
            int row = off >> 7, slot = off & 127;
            int srcs = slot ^ ((row & 7) << 4);
            __builtin_amdgcn_global_load_lds(AS1(Bsrc + (size_t)row * 1536 + srcs),
                                             AS3((char*)Bs + dstoff), 16, 0, 0);
        }
        __syncthreads();
        __builtin_amdgcn_s_setprio(1);
        #pragma unroll
        for (int h2 = 0; h2 < 2; ++h2) {
            bf16x8 af[2], bfr[4];
            const int cb = h2 * 64 + g * 16;
            #pragma unroll
            for (int i = 0; i < 2; ++i)
                af[i]  = lds_rd8(As, wm * 32 + i * 16 + l15, cb);
            #pragma unroll
            for (int j = 0; j < 4; ++j)
                bfr[j] = lds_rd8(Bs, wn * 64 + j * 16 + l15, cb);
            #pragma unroll
            for (int i = 0; i < 2; ++i)
                #pragma unroll
                for (int j = 0; j < 4; ++j)
                    acc[i][j] = MFMA16(af[i], bfr[j], acc[i][j]);
        }
        __builtin_amdgcn_s_setprio(0);
    }
    #pragma unroll
    for (int i = 0; i < 2; ++i)
        #pragma unroll
        for (int r = 0; r < 4; ++r) {
            int mm = m0 + wm * 32 + i * 16 + g * 4 + r;
            #pragma unroll
            for (int j = 0; j < 4; ++j) {
                int n = n0 + wn * 64 + j * 16 + l15;
                out[(size_t)mm * NE + n] = acc[i][j][r];
            }
        }
}

extern "C" void kernel_launch(void* const* d_in, const int* in_sizes, int n_in,
                              void* d_out, int out_size, void* d_ws, size_t ws_size,
                              hipStream_t stream) {
    const float* x     = (const float*)d_in[0];
    const int*   chain = (const int*)d_in[1];
    const void*  amask = d_in[2];
    const float* Wq = (const float*)d_in[3];
    const float* Wk = (const float*)d_in[4];
    const float* Wv = (const float*)d_in[5];
    const float* Wo = (const float*)d_in[6];
    float* out = (float*)d_out;

    const size_t QSZ = (size_t)NB * NH * NS * ND;
    char* w = (char*)d_ws;
    float* cos_t = (float*)w;  w += (size_t)NS * 32 * 4;
    float* sin_t = (float*)w;  w += (size_t)NS * 32 * 4;
    int*   mflag = (int*)w;    w += 256;
    short* xb    = (short*)w;  w += (size_t)8192 * 768 * 2;  // reused as aout later
    short* Wqt   = (short*)w;  w += (size_t)768 * 768 * 2;
    short* Wkt   = (short*)w;  w += (size_t)768 * 768 * 2;
    short* Wvt   = (short*)w;  w += (size_t)768 * 768 * 2;
    short* Wot   = (short*)w;  w += (size_t)768 * 768 * 2;
    short* q_raw = (short*)w;  w += QSZ * 2;
    short* k_raw = (short*)w;  w += QSZ * 2;
    short* vtr   = (short*)w;  w += QSZ * 2;
    short* aout  = xb;   // lifetime-disjoint reuse

    prep_kernel<<<dim3(65), dim3(256), 0, stream>>>(cos_t, sin_t,
                                                    (const unsigned char*)amask, mflag);
    convert_x_kernel<<<dim3(3072), dim3(256), 0, stream>>>(x, xb);
    convert_wt_kernel<<<dim3(12, 12, 4), dim3(256), 0, stream>>>(Wq, Wk, Wv, Wo, Wqt, Wkt, Wvt, Wot);
    gemm_qkv_kernel<<<dim3(6, 64, 3), dim3(256), 0, stream>>>(xb, Wqt, Wkt, Wvt, q_raw, k_raw, vtr);
    attn_fused_kernel<<<dim3(1536), dim3(256), 0, stream>>>(q_raw, k_raw, vtr, cos_t, sin_t,
                                                            chain, amask, mflag, aout);
    gemm_out_kernel<<<dim3(6, 128), dim3(256), 0, stream>>>(aout, Wot, out);
}